// Round 6
// baseline (297.541 us; speedup 1.0000x reference)
//
#include <hip/hip_runtime.h>
#include <hip/hip_bf16.h>
#include <stdint.h>

#define G_    128
#define NP_   1024
#define F_    16
#define K_    16
#define H_    64
#define L_    64
#define OUT_  128

#define SLAB    32
#define DSTRIDE 68            // floats; (4j+lane)%32 -> 2 lanes/bank (free)
#define JQ_     4             // j-range split factor
#define JLEN    (NP_ / JQ_)   // 256 j per block
#define NSLABQ  (JLEN / SLAB) // 8 slabs per block

typedef short  short8v  __attribute__((ext_vector_type(8)));
typedef short  short4v  __attribute__((ext_vector_type(4)));
typedef float  float4v  __attribute__((ext_vector_type(4)));

__device__ __forceinline__ uint16_t bf_rne(float f) {
    uint32_t u = __float_as_uint(f);
    return (uint16_t)((u + 0x7FFFu + ((u >> 16) & 1u)) >> 16);
}
__device__ __forceinline__ float bf_to_f(uint16_t h) {
    return __uint_as_float((uint32_t)h << 16);
}

// ---------------------------------------------------------------------------
// Kernel A: per-point u/v tables (unchanged).
// ---------------------------------------------------------------------------
__global__ __launch_bounds__(256) void uv_kernel(
    const float* __restrict__ x, const float* __restrict__ W1,
    const float* __restrict__ b1, float* __restrict__ u, float* __restrict__ v)
{
    const int lane = threadIdx.x & 63;
    const int wave = threadIdx.x >> 6;

    float wb[16], wd[16];
#pragma unroll
    for (int f = 0; f < 16; ++f) {
        float wt  = W1[f * 64 + lane];
        float wbo = W1[(16 + f) * 64 + lane];
        wb[f] = wbo;
        wd[f] = wt - wbo;
    }
    const float bias = b1[lane];

    const int base = blockIdx.x * 64 + wave * 16;
    for (int n = 0; n < 16; ++n) {
        const int p = base + n;
        const float4* xr = (const float4*)(x + (size_t)p * 16);
        float4 a0 = xr[0], a1 = xr[1], a2 = xr[2], a3 = xr[3];
        float xv[16] = {a0.x,a0.y,a0.z,a0.w, a1.x,a1.y,a1.z,a1.w,
                        a2.x,a2.y,a2.z,a2.w, a3.x,a3.y,a3.z,a3.w};
        float uu = bias, vv = 0.f;
#pragma unroll
        for (int f = 0; f < 16; ++f) {
            uu = fmaf(xv[f], wd[f], uu);
            vv = fmaf(xv[f], wb[f], vv);
        }
        u[(size_t)p * 64 + lane] = uu;
        v[(size_t)p * 64 + lane] = vv;
    }
}

// ---------------------------------------------------------------------------
// Kernel B: kNN quarter-scan via MFMA distance tiles.
// Block = 256 threads = 4 waves = 256 queries x 256-j quarter.
// grid = G*4(qchunk)*4(jq) = 2048 -> 4 blocks/CU (LDS 38.9KB) = 4 waves/SIMD.
// Scan is BRANCHLESS: med3 chain is a no-op when d >= hp[15].
// Partial top-16 stored as packed floats (low 8 bits = local j).
// ---------------------------------------------------------------------------
__global__ __launch_bounds__(256, 4) void knn_kernel(
    const float* __restrict__ x, float* __restrict__ part)
{
    __shared__ float    DT[4][SLAB * DSTRIDE];  // 34816 B (per-wave private)
    __shared__ uint16_t zh[SLAB * 24];
    __shared__ uint16_t zl[SLAB * 24];
    __shared__ float    sqs[JLEN];              // 1 KB

    const int b      = blockIdx.x;
    const int g      = b >> 4;
    const int qchunk = (b >> 2) & 3;
    const int jq     = b & 3;
    const float* xg  = x + (size_t)g * NP_ * F_;
    const int tid  = threadIdx.x;
    const int lane = tid & 63;
    const int wave = tid >> 6;

    // --- sq_j for this block's j-quarter (exact fp32), one row per thread ---
    {
        const float4* p = (const float4*)(xg + (size_t)(jq * JLEN + tid) * 16);
        float4 a = p[0], bb = p[1], c = p[2], d = p[3];
        float s = a.x*a.x + a.y*a.y + a.z*a.z + a.w*a.w;
        s += bb.x*bb.x + bb.y*bb.y + bb.z*bb.z + bb.w*bb.w;
        s += c.x*c.x + c.y*c.y + c.z*c.z + c.w*c.w;
        s += d.x*d.x + d.y*d.y + d.z*d.z + d.w*d.w;
        sqs[tid] = s;
    }

    // --- A fragments: wave's 64 query rows, 4 row-tiles of 16 ---
    const int qbase = qchunk * 256 + wave * 64;
    const int arow  = lane & 15;
    const int agrp  = lane >> 4;
    const int aoct  = agrp & 1;
    short8v a1[4], a2[4];
#pragma unroll
    for (int rt = 0; rt < 4; ++rt) {
        const float* src = xg + (size_t)(qbase + rt * 16 + arow) * 16 + aoct * 8;
        float4 f0 = ((const float4*)src)[0];
        float4 f1 = ((const float4*)src)[1];
        float fv[8] = {f0.x,f0.y,f0.z,f0.w, f1.x,f1.y,f1.z,f1.w};
        short8v h, l;
#pragma unroll
        for (int i = 0; i < 8; ++i) {
            uint16_t hb = bf_rne(fv[i]);
            h[i] = (short)hb;
            l[i] = (short)bf_rne(fv[i] - bf_to_f(hb));
        }
        short8v zz = {0,0,0,0,0,0,0,0};
        a1[rt] = (agrp < 2) ? h : l;
        a2[rt] = (agrp < 2) ? h : zz;
    }

    float hp[16];
#pragma unroll
    for (int m = 0; m < 16; ++m) hp[m] = __uint_as_float(0x7F000000u);

    float* dtw = DT[wave];
    const int bcol  = lane & 15;
    const int bgrp4 = (lane >> 4) & 1;

#pragma unroll
    for (int sl = 0; sl < NSLABQ; ++sl) {
        __syncthreads();
        // --- stage slab rows as bf16 hi/lo (32 rows x 4 quads) ---
        if (tid < SLAB * 4) {
            const int row = tid >> 2, q4 = tid & 3;
            const float4 f = *(const float4*)(
                xg + (size_t)(jq * JLEN + sl * SLAB + row) * 16 + q4 * 4);
            uint16_t h0 = bf_rne(f.x), h1 = bf_rne(f.y), h2 = bf_rne(f.z), h3 = bf_rne(f.w);
            short4v hv = {(short)h0, (short)h1, (short)h2, (short)h3};
            short4v lv = {(short)bf_rne(f.x - bf_to_f(h0)), (short)bf_rne(f.y - bf_to_f(h1)),
                          (short)bf_rne(f.z - bf_to_f(h2)), (short)bf_rne(f.w - bf_to_f(h3))};
            *(short4v*)&zh[row * 24 + q4 * 4] = hv;
            *(short4v*)&zl[row * 24 + q4 * 4] = lv;
        }
        __syncthreads();

        // --- MFMA distance tiles + fold + transpose-store to DT ---
#pragma unroll
        for (int ct = 0; ct < SLAB / 16; ++ct) {
            short8v b1v = *(const short8v*)&zh[(ct * 16 + bcol) * 24 + bgrp4 * 8];
            short8v b2v = *(const short8v*)&zl[(ct * 16 + bcol) * 24 + bgrp4 * 8];
            const float sqv = sqs[sl * SLAB + ct * 16 + bcol];
#pragma unroll
            for (int rt = 0; rt < 4; ++rt) {
                float4v acc = {0.f, 0.f, 0.f, 0.f};
                acc = __builtin_amdgcn_mfma_f32_16x16x32_bf16(a1[rt], b1v, acc, 0, 0, 0);
                acc = __builtin_amdgcn_mfma_f32_16x16x32_bf16(a2[rt], b2v, acc, 0, 0, 0);
                float4 outv;
                outv.x = fmaf(-2.f, acc[0], sqv);
                outv.y = fmaf(-2.f, acc[1], sqv);
                outv.z = fmaf(-2.f, acc[2], sqv);
                outv.w = fmaf(-2.f, acc[3], sqv);
                *(float4*)&dtw[(ct * 16 + bcol) * DSTRIDE + rt * 16 + (lane >> 4) * 4] = outv;
            }
        }
        asm volatile("s_waitcnt lgkmcnt(0)" ::: "memory");
        __builtin_amdgcn_sched_barrier(0);

        // --- branchless scan: lane owns query (qbase+lane) ---
        const float* dtr = dtw + lane;
#pragma unroll
        for (int j = 0; j < SLAB; ++j) {
            float d = dtr[j * DSTRIDE];
            const uint32_t jl = (uint32_t)(sl * SLAB + j);   // compile-time
            float dpf = __uint_as_float(
                (__float_as_uint(d) & 0xFFFFFF00u) | jl);
#pragma unroll
            for (int m = 15; m >= 1; --m)
                hp[m] = __builtin_amdgcn_fmed3f(dpf, hp[m - 1], hp[m]);
            hp[0] = fminf(hp[0], dpf);
        }
    }

    // --- store packed partial list: part[qglobal*64 + jq*16 + m] ---
    const size_t qg = (size_t)g * NP_ + qchunk * 256 + wave * 64 + lane;
    float* dst = part + qg * 64 + jq * 16;
#pragma unroll
    for (int m4 = 0; m4 < 4; ++m4) {
        float4 o = {hp[m4*4+0], hp[m4*4+1], hp[m4*4+2], hp[m4*4+3]};
        *(float4*)(dst + m4 * 4) = o;
    }
}

// ---------------------------------------------------------------------------
// Kernel B2: merge 4 quarter-wise top-16 lists -> global top-16 per query.
// Thread per query; 64 branchless chain-inserts. Quarter id folded into
// bits 8-9 (global j = bits 0..9).
// ---------------------------------------------------------------------------
__global__ __launch_bounds__(256) void merge_kernel(
    const float* __restrict__ part, int* __restrict__ idxw)
{
    const size_t p = (size_t)blockIdx.x * 256 + threadIdx.x;
    const float* src = part + p * 64;

    float hp[16];
#pragma unroll
    for (int m = 0; m < 16; ++m) hp[m] = __uint_as_float(0x7F000000u);

#pragma unroll
    for (int qtr = 0; qtr < 4; ++qtr) {
#pragma unroll
        for (int m4 = 0; m4 < 4; ++m4) {
            float4 v = *(const float4*)(src + qtr * 16 + m4 * 4);
            float e[4] = {v.x, v.y, v.z, v.w};
#pragma unroll
            for (int t = 0; t < 4; ++t) {
                uint32_t uu = __float_as_uint(e[t]);
                float key = __uint_as_float(
                    (uu & 0xFFFFFC00u) | ((uint32_t)qtr << 8) | (uu & 0xFFu));
#pragma unroll
                for (int m = 15; m >= 1; --m)
                    hp[m] = __builtin_amdgcn_fmed3f(key, hp[m - 1], hp[m]);
                hp[0] = fminf(hp[0], key);
            }
        }
    }

    int* row = idxw + p * K_;
#pragma unroll
    for (int m = 0; m < 16; ++m)
        row[m] = (int)(__float_as_uint(hp[m]) & 1023u);
}

// ---------------------------------------------------------------------------
// Kernel C: S[g][h] = sum_{i,k} relu(u_i[h] + v_{idx[i][k]}[h])  (unchanged)
// ---------------------------------------------------------------------------
__global__ __launch_bounds__(256) void gather_kernel(
    const float* __restrict__ u, const float* __restrict__ v,
    const int* __restrict__ idxw, float* __restrict__ S)
{
    const int lane = threadIdx.x & 63;
    const int wave = threadIdx.x >> 6;
    const int pbase = blockIdx.x * 128 + wave * 32;
    const int g = pbase >> 10;
    const float* vg = v + (((size_t)g << 10) << 6);
    float acc = 0.f;
    for (int n = 0; n < 32; ++n) {
        const int ii = pbase + n;
        const float uu = u[(size_t)ii * 64 + lane];
        const int4* irow = (const int4*)(idxw + (size_t)ii * 16);
#pragma unroll
        for (int q = 0; q < 4; ++q) {
            int4 j4 = irow[q];
            float v0 = vg[(size_t)j4.x * 64 + lane];
            float v1 = vg[(size_t)j4.y * 64 + lane];
            float v2 = vg[(size_t)j4.z * 64 + lane];
            float v3 = vg[(size_t)j4.w * 64 + lane];
            acc += fmaxf(0.f, uu + v0);
            acc += fmaxf(0.f, uu + v1);
            acc += fmaxf(0.f, uu + v2);
            acc += fmaxf(0.f, uu + v3);
        }
    }
    atomicAdd(&S[(g << 6) + lane], acc);
}

// ---------------------------------------------------------------------------
// Kernel D: per-group head (unchanged).
// ---------------------------------------------------------------------------
__global__ __launch_bounds__(128) void head_kernel(
    const float* __restrict__ S, const float* __restrict__ W2,
    const float* __restrict__ b2, const float* __restrict__ Wf,
    const float* __restrict__ bf, float* __restrict__ out)
{
    __shared__ float hbar[64];
    __shared__ float t[64];
    const int g = blockIdx.x;
    const int tid = threadIdx.x;
    if (tid < 64) hbar[tid] = S[g * 64 + tid] * (1.f / (1024.f * 16.f));
    __syncthreads();
    if (tid < 64) {
        float a = b2[tid];
        for (int h = 0; h < 64; ++h) a = fmaf(hbar[h], W2[h * 64 + tid], a);
        t[tid] = a;
    }
    __syncthreads();
    float a = bf[tid];
    for (int h = 0; h < 64; ++h) a = fmaf(t[h], Wf[h * 128 + tid], a);
    out[g * 128 + tid] = a;
}

// ---------------------------------------------------------------------------
extern "C" void kernel_launch(void* const* d_in, const int* in_sizes, int n_in,
                              void* d_out, int out_size, void* d_ws, size_t ws_size,
                              hipStream_t stream)
{
    const float* x  = (const float*)d_in[0];
    const float* W1 = (const float*)d_in[2];
    const float* b1 = (const float*)d_in[3];
    const float* W2 = (const float*)d_in[4];
    const float* b2 = (const float*)d_in[5];
    const float* Wf = (const float*)d_in[6];
    const float* bf = (const float*)d_in[7];
    float* out = (float*)d_out;

    char* ws = (char*)d_ws;
    const size_t N = (size_t)G_ * NP_;               // 131072
    float* u    = (float*)ws;                        // 32 MB
    float* v    = (float*)(ws + N * 64 * 4);         // 32 MB
    int*   idxw = (int*)  (ws + 2 * N * 64 * 4);     //  8 MB
    float* S    = (float*)(ws + 2 * N * 64 * 4 + N * 16 * 4);
    float* part = u;   // aliases u: lifetime (knn->merge) ends before uv writes u

    hipMemsetAsync(S, 0, G_ * H_ * sizeof(float), stream);

    knn_kernel   <<<G_ * 16, 256, 0, stream>>>(x, part);
    merge_kernel <<<(G_ * NP_) / 256, 256, 0, stream>>>(part, idxw);
    uv_kernel    <<<2048, 256, 0, stream>>>(x, W1, b1, u, v);
    gather_kernel<<<1024, 256, 0, stream>>>(u, v, idxw, S);
    head_kernel  <<<G_, 128, 0, stream>>>(S, W2, b2, Wf, bf, out);
}

// Round 7
// 191.415 us; speedup vs baseline: 1.5544x; 1.5544x over previous
//
#include <hip/hip_runtime.h>
#include <hip/hip_bf16.h>
#include <stdint.h>

#define G_    128
#define NP_   1024
#define F_    16
#define K_    16
#define H_    64
#define L_    64
#define OUT_  128

typedef short  short8v  __attribute__((ext_vector_type(8)));
typedef float  f32x16   __attribute__((ext_vector_type(16)));
typedef float  f32x4    __attribute__((ext_vector_type(4)));

__device__ __forceinline__ uint16_t bf_rne(float f) {
    uint32_t u = __float_as_uint(f);
    return (uint16_t)((u + 0x7FFFu + ((u >> 16) & 1u)) >> 16);
}
__device__ __forceinline__ float bf_to_f(uint16_t h) {
    return __uint_as_float((uint32_t)h << 16);
}

// ---------------------------------------------------------------------------
// Kernel A: per-point u/v tables (unchanged).
// ---------------------------------------------------------------------------
__global__ __launch_bounds__(256) void uv_kernel(
    const float* __restrict__ x, const float* __restrict__ W1,
    const float* __restrict__ b1, float* __restrict__ u, float* __restrict__ v)
{
    const int lane = threadIdx.x & 63;
    const int wave = threadIdx.x >> 6;

    float wb[16], wd[16];
#pragma unroll
    for (int f = 0; f < 16; ++f) {
        float wt  = W1[f * 64 + lane];
        float wbo = W1[(16 + f) * 64 + lane];
        wb[f] = wbo;
        wd[f] = wt - wbo;
    }
    const float bias = b1[lane];

    const int base = blockIdx.x * 64 + wave * 16;
    for (int n = 0; n < 16; ++n) {
        const int p = base + n;
        const float4* xr = (const float4*)(x + (size_t)p * 16);
        float4 a0 = xr[0], a1 = xr[1], a2 = xr[2], a3 = xr[3];
        float xv[16] = {a0.x,a0.y,a0.z,a0.w, a1.x,a1.y,a1.z,a1.w,
                        a2.x,a2.y,a2.z,a2.w, a3.x,a3.y,a3.z,a3.w};
        float uu = bias, vv = 0.f;
#pragma unroll
        for (int f = 0; f < 16; ++f) {
            uu = fmaf(xv[f], wd[f], uu);
            vv = fmaf(xv[f], wb[f], vv);
        }
        u[(size_t)p * 64 + lane] = uu;
        v[(size_t)p * 64 + lane] = vv;
    }
}

// ---------------------------------------------------------------------------
// Kernel B: kNN, distances kept entirely in registers.
// Block = 512 threads = 8 waves; block covers 256 queries; 4 blocks/group.
// Per wave: 32 queries (cols of a 32x32 MFMA tile). Per slab of 32 j:
//   acc = mfma32x32x16(Ah,Bl, mfma(Al,Bh, mfma(Ah,Bh, 0)))   (j-hi/lo, q-hi/lo,
//   -2 folded into B).  C layout: col(query)=lane&31,
//   row(j) = (reg&3)+8*(reg>>2)+4*(lane>>5)  -> lane q and q+32 each hold 16
//   of the 32 distances in acc regs. Each maintains its own sorted top-16
//   (index packed in low 10 mantissa bits); merged once at the end via
//   __shfl_xor(.,32) + one 16-insert chain. No distance ever touches memory.
// LDS: j-fragments (bf16 hi/lo) pre-swizzled in MFMA order + sq_j pre-arranged
// in (slab, half, reg) order (broadcast ds_read_b128).
// ---------------------------------------------------------------------------
__global__ __launch_bounds__(512, 4) void knn_kernel(
    const float* __restrict__ x, int* __restrict__ idxw)
{
    __shared__ uint16_t zh[2048 * 8];        // 32 KB  entry e = slab*64+lane
    __shared__ uint16_t zl[2048 * 8];        // 32 KB
    __shared__ float    sqarr[32 * 2 * 16];  //  4 KB  [slab][half][reg]

    const int b   = blockIdx.x;              // grid = G_*4 = 512
    const int g   = b >> 2;
    const float* xg = x + (size_t)g * NP_ * F_;
    const int tid  = threadIdx.x;
    const int lane = tid & 63;
    const int wave = tid >> 6;
    const int hi   = lane >> 5;              // which 16-j half this lane owns
    const int col  = lane & 31;              // query within wave tile

    // --- prologue: convert all 1024 j-rows to bf16 hi/lo in MFMA fragment
    //     order; compute sq_j into (slab,half,reg)-arranged table ---
#pragma unroll
    for (int rr = 0; rr < 2; ++rr) {
        const int row = tid * 2 + rr;        // 0..1023
        const float4* xr = (const float4*)(xg + (size_t)row * 16);
        float4 c0 = xr[0], c1 = xr[1], c2 = xr[2], c3 = xr[3];
        float fv[16] = {c0.x,c0.y,c0.z,c0.w, c1.x,c1.y,c1.z,c1.w,
                        c2.x,c2.y,c2.z,c2.w, c3.x,c3.y,c3.z,c3.w};
        float sq = 0.f;
#pragma unroll
        for (int e = 0; e < 16; ++e) sq = fmaf(fv[e], fv[e], sq);

        short8v hv0, hv1, lv0, lv1;
#pragma unroll
        for (int e = 0; e < 8; ++e) {
            uint16_t hb = bf_rne(fv[e]);
            hv0[e] = (short)hb;
            lv0[e] = (short)bf_rne(fv[e] - bf_to_f(hb));
        }
#pragma unroll
        for (int e = 0; e < 8; ++e) {
            uint16_t hb = bf_rne(fv[8 + e]);
            hv1[e] = (short)hb;
            lv1[e] = (short)bf_rne(fv[8 + e] - bf_to_f(hb));
        }
        const int e0 = ((row >> 5) << 6) + (row & 31);   // oct0 entry
        *(short8v*)&zh[(size_t)e0 * 8]        = hv0;
        *(short8v*)&zh[(size_t)(e0 + 32) * 8] = hv1;
        *(short8v*)&zl[(size_t)e0 * 8]        = lv0;
        *(short8v*)&zl[(size_t)(e0 + 32) * 8] = lv1;
        // inverse of jmap(r,h) = (r&3) + 8*(r>>2) + 4h
        const int s2 = ((row >> 5) << 1) + ((row >> 2) & 1);
        const int r  = (row & 3) | (((row >> 3) & 3) << 2);
        sqarr[s2 * 16 + r] = sq;
    }

    // --- query fragments: B col = query, k-octet = hi; scale by -2 ---
    const int qbase = (b & 3) * 256 + wave * 32;
    short8v Bh, Bl;
    {
        const float* qsrc = xg + (size_t)(qbase + col) * 16 + hi * 8;
        float4 q0 = ((const float4*)qsrc)[0];
        float4 q1 = ((const float4*)qsrc)[1];
        float qv[8] = {q0.x,q0.y,q0.z,q0.w, q1.x,q1.y,q1.z,q1.w};
#pragma unroll
        for (int e = 0; e < 8; ++e) {
            float m2 = -2.f * qv[e];
            uint16_t hb = bf_rne(m2);
            Bh[e] = (short)hb;
            Bl[e] = (short)bf_rne(m2 - bf_to_f(hb));
        }
    }

    float hp[16];
#pragma unroll
    for (int m = 0; m < 16; ++m) hp[m] = __uint_as_float(0x7F000000u);

    __syncthreads();

    const int hi4 = hi << 2;
#pragma unroll 4
    for (int s = 0; s < 32; ++s) {
        short8v Ah = *(const short8v*)&zh[(size_t)(s * 64 + lane) * 8];
        short8v Al = *(const short8v*)&zl[(size_t)(s * 64 + lane) * 8];
        const float* sqb = &sqarr[(s * 2 + hi) * 16];
        f32x4 s0 = *(const f32x4*)(sqb + 0);
        f32x4 s1 = *(const f32x4*)(sqb + 4);
        f32x4 s2 = *(const f32x4*)(sqb + 8);
        f32x4 s3 = *(const f32x4*)(sqb + 12);

        f32x16 acc = {0,0,0,0,0,0,0,0,0,0,0,0,0,0,0,0};
        acc = __builtin_amdgcn_mfma_f32_32x32x16_bf16(Ah, Bl, acc, 0, 0, 0); // hl
        acc = __builtin_amdgcn_mfma_f32_32x32x16_bf16(Al, Bh, acc, 0, 0, 0); // lh
        acc = __builtin_amdgcn_mfma_f32_32x32x16_bf16(Ah, Bh, acc, 0, 0, 0); // hh

        const uint32_t orb = ((uint32_t)s << 5) | (uint32_t)hi4;
#define KEY_INS(r, sqv)                                                       \
        {                                                                     \
            float d = acc[r] + (sqv);                                         \
            uint32_t kb = (__float_as_uint(d) & 0xFFFFFC00u) | orb            \
                          | (uint32_t)(((r) & 3) + 8 * ((r) >> 2));           \
            float kf = __uint_as_float(kb);                                   \
            _Pragma("unroll")                                                 \
            for (int m = 15; m >= 1; --m)                                     \
                hp[m] = __builtin_amdgcn_fmed3f(kf, hp[m - 1], hp[m]);        \
            hp[0] = fminf(hp[0], kf);                                         \
        }
        KEY_INS(0,  s0[0]) KEY_INS(1,  s0[1]) KEY_INS(2,  s0[2]) KEY_INS(3,  s0[3])
        KEY_INS(4,  s1[0]) KEY_INS(5,  s1[1]) KEY_INS(6,  s1[2]) KEY_INS(7,  s1[3])
        KEY_INS(8,  s2[0]) KEY_INS(9,  s2[1]) KEY_INS(10, s2[2]) KEY_INS(11, s2[3])
        KEY_INS(12, s3[0]) KEY_INS(13, s3[1]) KEY_INS(14, s3[2]) KEY_INS(15, s3[3])
#undef KEY_INS
    }

    // --- merge partner half (lane q <-> q+32), snapshot first ---
    float ot[16];
#pragma unroll
    for (int m = 0; m < 16; ++m) ot[m] = __shfl_xor(hp[m], 32);
#pragma unroll
    for (int m = 0; m < 16; ++m) {
        float kf = ot[m];
#pragma unroll
        for (int t = 15; t >= 1; --t)
            hp[t] = __builtin_amdgcn_fmed3f(kf, hp[t - 1], hp[t]);
        hp[0] = fminf(hp[0], kf);
    }

    if (lane < 32) {
        int* row = idxw + ((size_t)g * NP_ + qbase + col) * K_;
#pragma unroll
        for (int m4 = 0; m4 < 4; ++m4) {
            int4 o;
            o.x = (int)(__float_as_uint(hp[m4 * 4 + 0]) & 1023u);
            o.y = (int)(__float_as_uint(hp[m4 * 4 + 1]) & 1023u);
            o.z = (int)(__float_as_uint(hp[m4 * 4 + 2]) & 1023u);
            o.w = (int)(__float_as_uint(hp[m4 * 4 + 3]) & 1023u);
            *(int4*)(row + m4 * 4) = o;
        }
    }
}

// ---------------------------------------------------------------------------
// Kernel C: S[g][h] = sum_{i,k} relu(u_i[h] + v_{idx[i][k]}[h])  (unchanged)
// ---------------------------------------------------------------------------
__global__ __launch_bounds__(256) void gather_kernel(
    const float* __restrict__ u, const float* __restrict__ v,
    const int* __restrict__ idxw, float* __restrict__ S)
{
    const int lane = threadIdx.x & 63;
    const int wave = threadIdx.x >> 6;
    const int pbase = blockIdx.x * 128 + wave * 32;
    const int g = pbase >> 10;
    const float* vg = v + (((size_t)g << 10) << 6);
    float acc = 0.f;
    for (int n = 0; n < 32; ++n) {
        const int ii = pbase + n;
        const float uu = u[(size_t)ii * 64 + lane];
        const int4* irow = (const int4*)(idxw + (size_t)ii * 16);
#pragma unroll
        for (int q = 0; q < 4; ++q) {
            int4 j4 = irow[q];
            float v0 = vg[(size_t)j4.x * 64 + lane];
            float v1 = vg[(size_t)j4.y * 64 + lane];
            float v2 = vg[(size_t)j4.z * 64 + lane];
            float v3 = vg[(size_t)j4.w * 64 + lane];
            acc += fmaxf(0.f, uu + v0);
            acc += fmaxf(0.f, uu + v1);
            acc += fmaxf(0.f, uu + v2);
            acc += fmaxf(0.f, uu + v3);
        }
    }
    atomicAdd(&S[(g << 6) + lane], acc);
}

// ---------------------------------------------------------------------------
// Kernel D: per-group head (unchanged).
// ---------------------------------------------------------------------------
__global__ __launch_bounds__(128) void head_kernel(
    const float* __restrict__ S, const float* __restrict__ W2,
    const float* __restrict__ b2, const float* __restrict__ Wf,
    const float* __restrict__ bf, float* __restrict__ out)
{
    __shared__ float hbar[64];
    __shared__ float t[64];
    const int g = blockIdx.x;
    const int tid = threadIdx.x;
    if (tid < 64) hbar[tid] = S[g * 64 + tid] * (1.f / (1024.f * 16.f));
    __syncthreads();
    if (tid < 64) {
        float a = b2[tid];
        for (int h = 0; h < 64; ++h) a = fmaf(hbar[h], W2[h * 64 + tid], a);
        t[tid] = a;
    }
    __syncthreads();
    float a = bf[tid];
    for (int h = 0; h < 64; ++h) a = fmaf(t[h], Wf[h * 128 + tid], a);
    out[g * 128 + tid] = a;
}

// ---------------------------------------------------------------------------
extern "C" void kernel_launch(void* const* d_in, const int* in_sizes, int n_in,
                              void* d_out, int out_size, void* d_ws, size_t ws_size,
                              hipStream_t stream)
{
    const float* x  = (const float*)d_in[0];
    const float* W1 = (const float*)d_in[2];
    const float* b1 = (const float*)d_in[3];
    const float* W2 = (const float*)d_in[4];
    const float* b2 = (const float*)d_in[5];
    const float* Wf = (const float*)d_in[6];
    const float* bf = (const float*)d_in[7];
    float* out = (float*)d_out;

    char* ws = (char*)d_ws;
    const size_t N = (size_t)G_ * NP_;               // 131072
    float* u    = (float*)ws;                        // 32 MB
    float* v    = (float*)(ws + N * 64 * 4);         // 32 MB
    int*   idxw = (int*)  (ws + 2 * N * 64 * 4);     //  8 MB
    float* S    = (float*)(ws + 2 * N * 64 * 4 + N * 16 * 4);

    hipMemsetAsync(S, 0, G_ * H_ * sizeof(float), stream);

    knn_kernel   <<<G_ * 4, 512, 0, stream>>>(x, idxw);
    uv_kernel    <<<2048, 256, 0, stream>>>(x, W1, b1, u, v);
    gather_kernel<<<1024, 256, 0, stream>>>(u, v, idxw, S);
    head_kernel  <<<G_, 128, 0, stream>>>(S, W2, b2, Wf, bf, out);
}

// Round 9
// 163.302 us; speedup vs baseline: 1.8220x; 1.1722x over previous
//
#include <hip/hip_runtime.h>
#include <hip/hip_bf16.h>
#include <stdint.h>

#define G_    128
#define NP_   1024
#define F_    16
#define K_    16
#define H_    64
#define L_    64
#define OUT_  128

typedef short  short8v  __attribute__((ext_vector_type(8)));
typedef float  f32x16   __attribute__((ext_vector_type(16)));
typedef float  f32x4    __attribute__((ext_vector_type(4)));

__device__ __forceinline__ uint16_t bf_rne(float f) {
    uint32_t u = __float_as_uint(f);
    return (uint16_t)((u + 0x7FFFu + ((u >> 16) & 1u)) >> 16);
}
__device__ __forceinline__ float bf_to_f(uint16_t h) {
    return __uint_as_float((uint32_t)h << 16);
}

// ---------------------------------------------------------------------------
// Kernel B: kNN, distances kept entirely in registers. (R7 version, verbatim —
// passed bench + rocprof replays. Self-contained: no cross-kernel scratch.)
// Block = 512 threads = 8 waves; block covers 256 queries; 4 blocks/group.
// ---------------------------------------------------------------------------
__global__ __launch_bounds__(512, 4) void knn_kernel(
    const float* __restrict__ x, int* __restrict__ idxw)
{
    __shared__ uint16_t zh[2048 * 8];        // 32 KB  entry e = slab*64+lane
    __shared__ uint16_t zl[2048 * 8];        // 32 KB
    __shared__ float    sqarr[32 * 2 * 16];  //  4 KB  [slab][half][reg]

    const int b   = blockIdx.x;              // grid = G_*4 = 512
    const int g   = b >> 2;
    const float* xg = x + (size_t)g * NP_ * F_;
    const int tid  = threadIdx.x;
    const int lane = tid & 63;
    const int wave = tid >> 6;
    const int hi   = lane >> 5;              // which 16-j half this lane owns
    const int col  = lane & 31;              // query within wave tile

    // --- prologue: convert all 1024 j-rows to bf16 hi/lo in MFMA fragment
    //     order; compute sq_j into (slab,half,reg)-arranged table ---
#pragma unroll
    for (int rr = 0; rr < 2; ++rr) {
        const int row = tid * 2 + rr;        // 0..1023
        const float4* xr = (const float4*)(xg + (size_t)row * 16);
        float4 c0 = xr[0], c1 = xr[1], c2 = xr[2], c3 = xr[3];
        float fv[16] = {c0.x,c0.y,c0.z,c0.w, c1.x,c1.y,c1.z,c1.w,
                        c2.x,c2.y,c2.z,c2.w, c3.x,c3.y,c3.z,c3.w};
        float sq = 0.f;
#pragma unroll
        for (int e = 0; e < 16; ++e) sq = fmaf(fv[e], fv[e], sq);

        short8v hv0, hv1, lv0, lv1;
#pragma unroll
        for (int e = 0; e < 8; ++e) {
            uint16_t hb = bf_rne(fv[e]);
            hv0[e] = (short)hb;
            lv0[e] = (short)bf_rne(fv[e] - bf_to_f(hb));
        }
#pragma unroll
        for (int e = 0; e < 8; ++e) {
            uint16_t hb = bf_rne(fv[8 + e]);
            hv1[e] = (short)hb;
            lv1[e] = (short)bf_rne(fv[8 + e] - bf_to_f(hb));
        }
        const int e0 = ((row >> 5) << 6) + (row & 31);   // oct0 entry
        *(short8v*)&zh[(size_t)e0 * 8]        = hv0;
        *(short8v*)&zh[(size_t)(e0 + 32) * 8] = hv1;
        *(short8v*)&zl[(size_t)e0 * 8]        = lv0;
        *(short8v*)&zl[(size_t)(e0 + 32) * 8] = lv1;
        // inverse of jmap(r,h) = (r&3) + 8*(r>>2) + 4h
        const int s2 = ((row >> 5) << 1) + ((row >> 2) & 1);
        const int r  = (row & 3) | (((row >> 3) & 3) << 2);
        sqarr[s2 * 16 + r] = sq;
    }

    // --- query fragments: B col = query, k-octet = hi; scale by -2 ---
    const int qbase = (b & 3) * 256 + wave * 32;
    short8v Bh, Bl;
    {
        const float* qsrc = xg + (size_t)(qbase + col) * 16 + hi * 8;
        float4 q0 = ((const float4*)qsrc)[0];
        float4 q1 = ((const float4*)qsrc)[1];
        float qv[8] = {q0.x,q0.y,q0.z,q0.w, q1.x,q1.y,q1.z,q1.w};
#pragma unroll
        for (int e = 0; e < 8; ++e) {
            float m2 = -2.f * qv[e];
            uint16_t hb = bf_rne(m2);
            Bh[e] = (short)hb;
            Bl[e] = (short)bf_rne(m2 - bf_to_f(hb));
        }
    }

    float hp[16];
#pragma unroll
    for (int m = 0; m < 16; ++m) hp[m] = __uint_as_float(0x7F000000u);

    __syncthreads();

    const int hi4 = hi << 2;
#pragma unroll 4
    for (int s = 0; s < 32; ++s) {
        short8v Ah = *(const short8v*)&zh[(size_t)(s * 64 + lane) * 8];
        short8v Al = *(const short8v*)&zl[(size_t)(s * 64 + lane) * 8];
        const float* sqb = &sqarr[(s * 2 + hi) * 16];
        f32x4 s0 = *(const f32x4*)(sqb + 0);
        f32x4 s1 = *(const f32x4*)(sqb + 4);
        f32x4 s2 = *(const f32x4*)(sqb + 8);
        f32x4 s3 = *(const f32x4*)(sqb + 12);

        f32x16 acc = {0,0,0,0,0,0,0,0,0,0,0,0,0,0,0,0};
        acc = __builtin_amdgcn_mfma_f32_32x32x16_bf16(Ah, Bl, acc, 0, 0, 0); // hl
        acc = __builtin_amdgcn_mfma_f32_32x32x16_bf16(Al, Bh, acc, 0, 0, 0); // lh
        acc = __builtin_amdgcn_mfma_f32_32x32x16_bf16(Ah, Bh, acc, 0, 0, 0); // hh

        const uint32_t orb = ((uint32_t)s << 5) | (uint32_t)hi4;
#define KEY_INS(r, sqv)                                                       \
        {                                                                     \
            float d = acc[r] + (sqv);                                         \
            uint32_t kb = (__float_as_uint(d) & 0xFFFFFC00u) | orb            \
                          | (uint32_t)(((r) & 3) + 8 * ((r) >> 2));           \
            float kf = __uint_as_float(kb);                                   \
            _Pragma("unroll")                                                 \
            for (int m = 15; m >= 1; --m)                                     \
                hp[m] = __builtin_amdgcn_fmed3f(kf, hp[m - 1], hp[m]);        \
            hp[0] = fminf(hp[0], kf);                                         \
        }
        KEY_INS(0,  s0[0]) KEY_INS(1,  s0[1]) KEY_INS(2,  s0[2]) KEY_INS(3,  s0[3])
        KEY_INS(4,  s1[0]) KEY_INS(5,  s1[1]) KEY_INS(6,  s1[2]) KEY_INS(7,  s1[3])
        KEY_INS(8,  s2[0]) KEY_INS(9,  s2[1]) KEY_INS(10, s2[2]) KEY_INS(11, s2[3])
        KEY_INS(12, s3[0]) KEY_INS(13, s3[1]) KEY_INS(14, s3[2]) KEY_INS(15, s3[3])
#undef KEY_INS
    }

    // --- merge partner half (lane q <-> q+32), snapshot first ---
    float ot[16];
#pragma unroll
    for (int m = 0; m < 16; ++m) ot[m] = __shfl_xor(hp[m], 32);
#pragma unroll
    for (int m = 0; m < 16; ++m) {
        float kf = ot[m];
#pragma unroll
        for (int t = 15; t >= 1; --t)
            hp[t] = __builtin_amdgcn_fmed3f(kf, hp[t - 1], hp[t]);
        hp[0] = fminf(hp[0], kf);
    }

    if (lane < 32) {
        int* row = idxw + ((size_t)g * NP_ + qbase + col) * K_;
#pragma unroll
        for (int m4 = 0; m4 < 4; ++m4) {
            int4 o;
            o.x = (int)(__float_as_uint(hp[m4 * 4 + 0]) & 1023u);
            o.y = (int)(__float_as_uint(hp[m4 * 4 + 1]) & 1023u);
            o.z = (int)(__float_as_uint(hp[m4 * 4 + 2]) & 1023u);
            o.w = (int)(__float_as_uint(hp[m4 * 4 + 3]) & 1023u);
            *(int4*)(row + m4 * 4) = o;
        }
    }
}

// ---------------------------------------------------------------------------
// v-only: v[p][h] = sum_f x[p][f] * W1[16+f][h]
// ---------------------------------------------------------------------------
__global__ __launch_bounds__(256) void v_kernel(
    const float* __restrict__ x, const float* __restrict__ W1,
    float* __restrict__ v)
{
    const int lane = threadIdx.x & 63;
    const int wave = threadIdx.x >> 6;

    float wb[16];
#pragma unroll
    for (int f = 0; f < 16; ++f) wb[f] = W1[(16 + f) * 64 + lane];

    const int base = blockIdx.x * 64 + wave * 16;
    for (int n = 0; n < 16; ++n) {
        const int p = base + n;
        const float4* xr = (const float4*)(x + (size_t)p * 16);
        float4 a0 = xr[0], a1 = xr[1], a2 = xr[2], a3 = xr[3];
        float xv[16] = {a0.x,a0.y,a0.z,a0.w, a1.x,a1.y,a1.z,a1.w,
                        a2.x,a2.y,a2.z,a2.w, a3.x,a3.y,a3.z,a3.w};
        float vv = 0.f;
#pragma unroll
        for (int f = 0; f < 16; ++f) vv = fmaf(xv[f], wb[f], vv);
        v[(size_t)p * 64 + lane] = vv;
    }
}

// ---------------------------------------------------------------------------
// gather: per-(block,wave) partial  P[(g*8+chunk)*4+wave][h] =
//   sum_{i in 32-pt range, k} relu(u_i[h] + v_{idx[i][k]}[h]).
// u computed inline from x (no u round-trip). XCD-swizzled so a group's 8
// blocks co-reside -> v-slice (256KB) fetched ~once per group. NO atomics,
// NO zero-init dependence: every P row written exactly once per call.
// ---------------------------------------------------------------------------
__global__ __launch_bounds__(256) void gather_kernel(
    const float* __restrict__ x, const float* __restrict__ W1,
    const float* __restrict__ b1, const float* __restrict__ v,
    const int* __restrict__ idxw, float* __restrict__ P)
{
    const int lane = threadIdx.x & 63;
    const int wave = threadIdx.x >> 6;
    const int b    = blockIdx.x;
    const int xcd  = b & 7, slot = b >> 3;
    const int g    = xcd + ((slot & 15) << 3);
    const int chunk = slot >> 4;                       // 0..7
    const int pbase = g * NP_ + chunk * 128 + wave * 32;

    float wd[16];
#pragma unroll
    for (int f = 0; f < 16; ++f)
        wd[f] = W1[f * 64 + lane] - W1[(16 + f) * 64 + lane];
    const float bias = b1[lane];

    const float* vg = v + ((size_t)g << 16);
    float acc = 0.f;
    for (int n = 0; n < 32; ++n) {
        const int ii = pbase + n;
        const float4* xr = (const float4*)(x + (size_t)ii * 16);
        float4 c0 = xr[0], c1 = xr[1], c2 = xr[2], c3 = xr[3];
        float uu = bias;
        uu = fmaf(c0.x, wd[0],  uu); uu = fmaf(c0.y, wd[1],  uu);
        uu = fmaf(c0.z, wd[2],  uu); uu = fmaf(c0.w, wd[3],  uu);
        uu = fmaf(c1.x, wd[4],  uu); uu = fmaf(c1.y, wd[5],  uu);
        uu = fmaf(c1.z, wd[6],  uu); uu = fmaf(c1.w, wd[7],  uu);
        uu = fmaf(c2.x, wd[8],  uu); uu = fmaf(c2.y, wd[9],  uu);
        uu = fmaf(c2.z, wd[10], uu); uu = fmaf(c2.w, wd[11], uu);
        uu = fmaf(c3.x, wd[12], uu); uu = fmaf(c3.y, wd[13], uu);
        uu = fmaf(c3.z, wd[14], uu); uu = fmaf(c3.w, wd[15], uu);

        const int4* irow = (const int4*)(idxw + (size_t)ii * 16);
#pragma unroll
        for (int q = 0; q < 4; ++q) {
            int4 j4 = irow[q];
            float v0 = vg[((size_t)j4.x << 6) + lane];
            float v1 = vg[((size_t)j4.y << 6) + lane];
            float v2 = vg[((size_t)j4.z << 6) + lane];
            float v3 = vg[((size_t)j4.w << 6) + lane];
            acc += fmaxf(0.f, uu + v0);
            acc += fmaxf(0.f, uu + v1);
            acc += fmaxf(0.f, uu + v2);
            acc += fmaxf(0.f, uu + v3);
        }
    }
    P[(size_t)(((g << 3) + chunk) * 4 + wave) * 64 + lane] = acc;
}

// ---------------------------------------------------------------------------
// head: S[g][h] = sum of 32 partial rows; out[g] = ((S/(NP*K))@W2+b2)@Wf+bf
// ---------------------------------------------------------------------------
__global__ __launch_bounds__(128) void head_kernel(
    const float* __restrict__ P, const float* __restrict__ W2,
    const float* __restrict__ b2, const float* __restrict__ Wf,
    const float* __restrict__ bf, float* __restrict__ out)
{
    __shared__ float hbar[64];
    __shared__ float t[64];
    const int g = blockIdx.x;
    const int tid = threadIdx.x;
    if (tid < 64) {
        float s = 0.f;
        const float* pr = P + (size_t)g * 32 * 64 + tid;
#pragma unroll
        for (int i = 0; i < 32; ++i) s += pr[i * 64];
        hbar[tid] = s * (1.f / (1024.f * 16.f));
    }
    __syncthreads();
    if (tid < 64) {
        float a = b2[tid];
        for (int h = 0; h < 64; ++h) a = fmaf(hbar[h], W2[h * 64 + tid], a);
        t[tid] = a;
    }
    __syncthreads();
    float a = bf[tid];
    for (int h = 0; h < 64; ++h) a = fmaf(t[h], Wf[h * 128 + tid], a);
    out[g * 128 + tid] = a;
}

// ---------------------------------------------------------------------------
extern "C" void kernel_launch(void* const* d_in, const int* in_sizes, int n_in,
                              void* d_out, int out_size, void* d_ws, size_t ws_size,
                              hipStream_t stream)
{
    const float* x  = (const float*)d_in[0];
    const float* W1 = (const float*)d_in[2];
    const float* b1 = (const float*)d_in[3];
    const float* W2 = (const float*)d_in[4];
    const float* b2 = (const float*)d_in[5];
    const float* Wf = (const float*)d_in[6];
    const float* bf = (const float*)d_in[7];
    float* out = (float*)d_out;

    char* ws = (char*)d_ws;
    const size_t MB = 1024 * 1024;
    float* v    = (float*)ws;                   //  0 .. 32MB  (131072 x 64 f32)
    int*   idxw = (int*)(ws + 32 * MB);         // 32 .. 40MB  (131072 x 16 i32)
    float* P    = (float*)(ws + 40 * MB);       // 40 .. 41MB  (4096 x 64 f32)

    knn_kernel   <<<G_ * 4, 512, 0, stream>>>(x, idxw);
    v_kernel     <<<2048, 256, 0, stream>>>(x, W1, v);
    gather_kernel<<<G_ * 8, 256, 0, stream>>>(x, W1, b1, v, idxw, P);
    head_kernel  <<<G_, 128, 0, stream>>>(P, W2, b2, Wf, bf, out);
}

// Round 10
// 148.522 us; speedup vs baseline: 2.0033x; 1.0995x over previous
//
#include <hip/hip_runtime.h>
#include <hip/hip_bf16.h>
#include <stdint.h>

#define G_    128
#define NP_   1024
#define F_    16
#define K_    16
#define H_    64
#define L_    64
#define OUT_  128

typedef short  short8v  __attribute__((ext_vector_type(8)));
typedef float  f32x16   __attribute__((ext_vector_type(16)));
typedef float  f32x4    __attribute__((ext_vector_type(4)));

__device__ __forceinline__ uint16_t bf_rne(float f) {
    uint32_t u = __float_as_uint(f);
    return (uint16_t)((u + 0x7FFFu + ((u >> 16) & 1u)) >> 16);
}
__device__ __forceinline__ float bf_to_f(uint16_t h) {
    return __uint_as_float((uint32_t)h << 16);
}

// ---------------------------------------------------------------------------
// Kernel B: kNN, distances kept entirely in registers. Structure = R9
// (passed twice); scan phase rewritten: med3 insert chain -> min/max
// sorting network (Batcher OEMS-16 + half-cleaner + bitonic clean),
// sq_j folded into MFMA C-init.
// Block = 512 threads = 8 waves; block covers 256 queries; 4 blocks/group.
// ---------------------------------------------------------------------------
__global__ __launch_bounds__(512, 4) void knn_kernel(
    const float* __restrict__ x, int* __restrict__ idxw)
{
    __shared__ uint16_t zh[2048 * 8];        // 32 KB  entry e = slab*64+lane
    __shared__ uint16_t zl[2048 * 8];        // 32 KB
    __shared__ float    sqarr[32 * 2 * 16];  //  4 KB  [slab][half][reg]

    const int b   = blockIdx.x;              // grid = G_*4 = 512
    const int g   = b >> 2;
    const float* xg = x + (size_t)g * NP_ * F_;
    const int tid  = threadIdx.x;
    const int lane = tid & 63;
    const int wave = tid >> 6;
    const int hi   = lane >> 5;              // which 16-j half this lane owns
    const int col  = lane & 31;              // query within wave tile

    // --- prologue: convert all 1024 j-rows to bf16 hi/lo in MFMA fragment
    //     order; compute sq_j into (slab,half,reg)-arranged table ---
#pragma unroll
    for (int rr = 0; rr < 2; ++rr) {
        const int row = tid * 2 + rr;        // 0..1023
        const float4* xr = (const float4*)(xg + (size_t)row * 16);
        float4 c0 = xr[0], c1 = xr[1], c2 = xr[2], c3 = xr[3];
        float fv[16] = {c0.x,c0.y,c0.z,c0.w, c1.x,c1.y,c1.z,c1.w,
                        c2.x,c2.y,c2.z,c2.w, c3.x,c3.y,c3.z,c3.w};
        float sq = 0.f;
#pragma unroll
        for (int e = 0; e < 16; ++e) sq = fmaf(fv[e], fv[e], sq);

        short8v hv0, hv1, lv0, lv1;
#pragma unroll
        for (int e = 0; e < 8; ++e) {
            uint16_t hb = bf_rne(fv[e]);
            hv0[e] = (short)hb;
            lv0[e] = (short)bf_rne(fv[e] - bf_to_f(hb));
        }
#pragma unroll
        for (int e = 0; e < 8; ++e) {
            uint16_t hb = bf_rne(fv[8 + e]);
            hv1[e] = (short)hb;
            lv1[e] = (short)bf_rne(fv[8 + e] - bf_to_f(hb));
        }
        const int e0 = ((row >> 5) << 6) + (row & 31);   // oct0 entry
        *(short8v*)&zh[(size_t)e0 * 8]        = hv0;
        *(short8v*)&zh[(size_t)(e0 + 32) * 8] = hv1;
        *(short8v*)&zl[(size_t)e0 * 8]        = lv0;
        *(short8v*)&zl[(size_t)(e0 + 32) * 8] = lv1;
        // inverse of jmap(r,h) = (r&3) + 8*(r>>2) + 4h
        const int s2 = ((row >> 5) << 1) + ((row >> 2) & 1);
        const int r  = (row & 3) | (((row >> 3) & 3) << 2);
        sqarr[s2 * 16 + r] = sq;
    }

    // --- query fragments: B col = query, k-octet = hi; scale by -2 ---
    const int qbase = (b & 3) * 256 + wave * 32;
    short8v Bh, Bl;
    {
        const float* qsrc = xg + (size_t)(qbase + col) * 16 + hi * 8;
        float4 q0 = ((const float4*)qsrc)[0];
        float4 q1 = ((const float4*)qsrc)[1];
        float qv[8] = {q0.x,q0.y,q0.z,q0.w, q1.x,q1.y,q1.z,q1.w};
#pragma unroll
        for (int e = 0; e < 8; ++e) {
            float m2 = -2.f * qv[e];
            uint16_t hb = bf_rne(m2);
            Bh[e] = (short)hb;
            Bl[e] = (short)bf_rne(m2 - bf_to_f(hb));
        }
    }

    float hp[16];
#pragma unroll
    for (int m = 0; m < 16; ++m) hp[m] = __uint_as_float(0x7F000000u);

    __syncthreads();

    const int hi4 = hi << 2;

    // compare-exchange (ascending): 1 v_min + 1 v_max, full-rate
#define CE(a, i, j) { float t_lo = fminf(a[i], a[j]);                         \
                      float t_hi = fmaxf(a[i], a[j]);                         \
                      a[i] = t_lo; a[j] = t_hi; }

#pragma unroll 2
    for (int s = 0; s < 32; ++s) {
        short8v Ah = *(const short8v*)&zh[(size_t)(s * 64 + lane) * 8];
        short8v Al = *(const short8v*)&zl[(size_t)(s * 64 + lane) * 8];
        const float* sqb = &sqarr[(s * 2 + hi) * 16];
        f32x4 q0 = *(const f32x4*)(sqb + 0);
        f32x4 q1 = *(const f32x4*)(sqb + 4);
        f32x4 q2 = *(const f32x4*)(sqb + 8);
        f32x4 q3 = *(const f32x4*)(sqb + 12);

        // C-init carries sq_j: acc = sq_j - 2*dot after the 3 MFMAs
        f32x16 acc = {q0[0],q0[1],q0[2],q0[3], q1[0],q1[1],q1[2],q1[3],
                      q2[0],q2[1],q2[2],q2[3], q3[0],q3[1],q3[2],q3[3]};
        acc = __builtin_amdgcn_mfma_f32_32x32x16_bf16(Ah, Bl, acc, 0, 0, 0); // hl
        acc = __builtin_amdgcn_mfma_f32_32x32x16_bf16(Al, Bh, acc, 0, 0, 0); // lh
        acc = __builtin_amdgcn_mfma_f32_32x32x16_bf16(Ah, Bh, acc, 0, 0, 0); // hh

        // pack index into low 10 mantissa bits: (d & ~1023) | j
        const uint32_t jb = ((uint32_t)s << 5) | (uint32_t)hi4;
        float kk[16];
#pragma unroll
        for (int r = 0; r < 16; ++r) {
            uint32_t jv = jb | (uint32_t)((r & 3) + 8 * (r >> 2));
            kk[r] = __uint_as_float((__float_as_uint(acc[r]) & 0xFFFFFC00u) | jv);
        }

        // Batcher odd-even mergesort, 16 keys ascending (63 CE, hand-listed)
        CE(kk,0,1)  CE(kk,2,3)  CE(kk,4,5)  CE(kk,6,7)
        CE(kk,8,9)  CE(kk,10,11) CE(kk,12,13) CE(kk,14,15)
        CE(kk,0,2)  CE(kk,1,3)  CE(kk,4,6)  CE(kk,5,7)
        CE(kk,8,10) CE(kk,9,11) CE(kk,12,14) CE(kk,13,15)
        CE(kk,1,2)  CE(kk,5,6)  CE(kk,9,10) CE(kk,13,14)
        CE(kk,0,4)  CE(kk,1,5)  CE(kk,2,6)  CE(kk,3,7)
        CE(kk,8,12) CE(kk,9,13) CE(kk,10,14) CE(kk,11,15)
        CE(kk,2,4)  CE(kk,3,5)  CE(kk,10,12) CE(kk,11,13)
        CE(kk,1,2)  CE(kk,3,4)  CE(kk,5,6)
        CE(kk,9,10) CE(kk,11,12) CE(kk,13,14)
        CE(kk,0,8)  CE(kk,1,9)  CE(kk,2,10) CE(kk,3,11)
        CE(kk,4,12) CE(kk,5,13) CE(kk,6,14) CE(kk,7,15)
        CE(kk,4,8)  CE(kk,5,9)  CE(kk,6,10) CE(kk,7,11)
        CE(kk,2,4)  CE(kk,3,5)  CE(kk,6,8)  CE(kk,7,9)
        CE(kk,10,12) CE(kk,11,13)
        CE(kk,1,2)  CE(kk,3,4)  CE(kk,5,6)  CE(kk,7,8)
        CE(kk,9,10) CE(kk,11,12) CE(kk,13,14)

        // half-cleaner vs running top-16 (both ascending): keep 16 smallest
        float c[16];
#pragma unroll
        for (int i = 0; i < 16; ++i) c[i] = fminf(hp[i], kk[15 - i]);
        // c is bitonic -> 4-stage bitonic merge (32 CE)
        CE(c,0,8)  CE(c,1,9)  CE(c,2,10) CE(c,3,11)
        CE(c,4,12) CE(c,5,13) CE(c,6,14) CE(c,7,15)
        CE(c,0,4)  CE(c,1,5)  CE(c,2,6)  CE(c,3,7)
        CE(c,8,12) CE(c,9,13) CE(c,10,14) CE(c,11,15)
        CE(c,0,2)  CE(c,1,3)  CE(c,4,6)  CE(c,5,7)
        CE(c,8,10) CE(c,9,11) CE(c,12,14) CE(c,13,15)
        CE(c,0,1)  CE(c,2,3)  CE(c,4,5)  CE(c,6,7)
        CE(c,8,9)  CE(c,10,11) CE(c,12,13) CE(c,14,15)
#pragma unroll
        for (int i = 0; i < 16; ++i) hp[i] = c[i];
    }
#undef CE

    // --- merge partner half (lane q <-> q+32), snapshot first ---
    float ot[16];
#pragma unroll
    for (int m = 0; m < 16; ++m) ot[m] = __shfl_xor(hp[m], 32);
#pragma unroll
    for (int m = 0; m < 16; ++m) {
        float kf = ot[m];
#pragma unroll
        for (int t = 15; t >= 1; --t)
            hp[t] = __builtin_amdgcn_fmed3f(kf, hp[t - 1], hp[t]);
        hp[0] = fminf(hp[0], kf);
    }

    if (lane < 32) {
        int* row = idxw + ((size_t)g * NP_ + qbase + col) * K_;
#pragma unroll
        for (int m4 = 0; m4 < 4; ++m4) {
            int4 o;
            o.x = (int)(__float_as_uint(hp[m4 * 4 + 0]) & 1023u);
            o.y = (int)(__float_as_uint(hp[m4 * 4 + 1]) & 1023u);
            o.z = (int)(__float_as_uint(hp[m4 * 4 + 2]) & 1023u);
            o.w = (int)(__float_as_uint(hp[m4 * 4 + 3]) & 1023u);
            *(int4*)(row + m4 * 4) = o;
        }
    }
}

// ---------------------------------------------------------------------------
// v-only: v[p][h] = sum_f x[p][f] * W1[16+f][h]   (R9 verbatim)
// ---------------------------------------------------------------------------
__global__ __launch_bounds__(256) void v_kernel(
    const float* __restrict__ x, const float* __restrict__ W1,
    float* __restrict__ v)
{
    const int lane = threadIdx.x & 63;
    const int wave = threadIdx.x >> 6;

    float wb[16];
#pragma unroll
    for (int f = 0; f < 16; ++f) wb[f] = W1[(16 + f) * 64 + lane];

    const int base = blockIdx.x * 64 + wave * 16;
    for (int n = 0; n < 16; ++n) {
        const int p = base + n;
        const float4* xr = (const float4*)(x + (size_t)p * 16);
        float4 a0 = xr[0], a1 = xr[1], a2 = xr[2], a3 = xr[3];
        float xv[16] = {a0.x,a0.y,a0.z,a0.w, a1.x,a1.y,a1.z,a1.w,
                        a2.x,a2.y,a2.z,a2.w, a3.x,a3.y,a3.z,a3.w};
        float vv = 0.f;
#pragma unroll
        for (int f = 0; f < 16; ++f) vv = fmaf(xv[f], wb[f], vv);
        v[(size_t)p * 64 + lane] = vv;
    }
}

// ---------------------------------------------------------------------------
// gather: per-(block,wave) partials, no atomics   (R9 verbatim)
// ---------------------------------------------------------------------------
__global__ __launch_bounds__(256) void gather_kernel(
    const float* __restrict__ x, const float* __restrict__ W1,
    const float* __restrict__ b1, const float* __restrict__ v,
    const int* __restrict__ idxw, float* __restrict__ P)
{
    const int lane = threadIdx.x & 63;
    const int wave = threadIdx.x >> 6;
    const int b    = blockIdx.x;
    const int xcd  = b & 7, slot = b >> 3;
    const int g    = xcd + ((slot & 15) << 3);
    const int chunk = slot >> 4;                       // 0..7
    const int pbase = g * NP_ + chunk * 128 + wave * 32;

    float wd[16];
#pragma unroll
    for (int f = 0; f < 16; ++f)
        wd[f] = W1[f * 64 + lane] - W1[(16 + f) * 64 + lane];
    const float bias = b1[lane];

    const float* vg = v + ((size_t)g << 16);
    float acc = 0.f;
    for (int n = 0; n < 32; ++n) {
        const int ii = pbase + n;
        const float4* xr = (const float4*)(x + (size_t)ii * 16);
        float4 c0 = xr[0], c1 = xr[1], c2 = xr[2], c3 = xr[3];
        float uu = bias;
        uu = fmaf(c0.x, wd[0],  uu); uu = fmaf(c0.y, wd[1],  uu);
        uu = fmaf(c0.z, wd[2],  uu); uu = fmaf(c0.w, wd[3],  uu);
        uu = fmaf(c1.x, wd[4],  uu); uu = fmaf(c1.y, wd[5],  uu);
        uu = fmaf(c1.z, wd[6],  uu); uu = fmaf(c1.w, wd[7],  uu);
        uu = fmaf(c2.x, wd[8],  uu); uu = fmaf(c2.y, wd[9],  uu);
        uu = fmaf(c2.z, wd[10], uu); uu = fmaf(c2.w, wd[11], uu);
        uu = fmaf(c3.x, wd[12], uu); uu = fmaf(c3.y, wd[13], uu);
        uu = fmaf(c3.z, wd[14], uu); uu = fmaf(c3.w, wd[15], uu);

        const int4* irow = (const int4*)(idxw + (size_t)ii * 16);
#pragma unroll
        for (int q = 0; q < 4; ++q) {
            int4 j4 = irow[q];
            float v0 = vg[((size_t)j4.x << 6) + lane];
            float v1 = vg[((size_t)j4.y << 6) + lane];
            float v2 = vg[((size_t)j4.z << 6) + lane];
            float v3 = vg[((size_t)j4.w << 6) + lane];
            acc += fmaxf(0.f, uu + v0);
            acc += fmaxf(0.f, uu + v1);
            acc += fmaxf(0.f, uu + v2);
            acc += fmaxf(0.f, uu + v3);
        }
    }
    P[(size_t)(((g << 3) + chunk) * 4 + wave) * 64 + lane] = acc;
}

// ---------------------------------------------------------------------------
// head: S[g][h] = sum of 32 partial rows; out = ((S/(NP*K))@W2+b2)@Wf+bf
// (R9 verbatim)
// ---------------------------------------------------------------------------
__global__ __launch_bounds__(128) void head_kernel(
    const float* __restrict__ P, const float* __restrict__ W2,
    const float* __restrict__ b2, const float* __restrict__ Wf,
    const float* __restrict__ bf, float* __restrict__ out)
{
    __shared__ float hbar[64];
    __shared__ float t[64];
    const int g = blockIdx.x;
    const int tid = threadIdx.x;
    if (tid < 64) {
        float s = 0.f;
        const float* pr = P + (size_t)g * 32 * 64 + tid;
#pragma unroll
        for (int i = 0; i < 32; ++i) s += pr[i * 64];
        hbar[tid] = s * (1.f / (1024.f * 16.f));
    }
    __syncthreads();
    if (tid < 64) {
        float a = b2[tid];
        for (int h = 0; h < 64; ++h) a = fmaf(hbar[h], W2[h * 64 + tid], a);
        t[tid] = a;
    }
    __syncthreads();
    float a = bf[tid];
    for (int h = 0; h < 64; ++h) a = fmaf(t[h], Wf[h * 128 + tid], a);
    out[g * 128 + tid] = a;
}

// ---------------------------------------------------------------------------
extern "C" void kernel_launch(void* const* d_in, const int* in_sizes, int n_in,
                              void* d_out, int out_size, void* d_ws, size_t ws_size,
                              hipStream_t stream)
{
    const float* x  = (const float*)d_in[0];
    const float* W1 = (const float*)d_in[2];
    const float* b1 = (const float*)d_in[3];
    const float* W2 = (const float*)d_in[4];
    const float* b2 = (const float*)d_in[5];
    const float* Wf = (const float*)d_in[6];
    const float* bf = (const float*)d_in[7];
    float* out = (float*)d_out;

    char* ws = (char*)d_ws;
    const size_t MB = 1024 * 1024;
    float* v    = (float*)ws;                   //  0 .. 32MB  (131072 x 64 f32)
    int*   idxw = (int*)(ws + 32 * MB);         // 32 .. 40MB  (131072 x 16 i32)
    float* P    = (float*)(ws + 40 * MB);       // 40 .. 41MB  (4096 x 64 f32)

    knn_kernel   <<<G_ * 4, 512, 0, stream>>>(x, idxw);
    v_kernel     <<<2048, 256, 0, stream>>>(x, W1, v);
    gather_kernel<<<G_ * 8, 256, 0, stream>>>(x, W1, b1, v, idxw, P);
    head_kernel  <<<G_, 128, 0, stream>>>(P, W2, b2, Wf, bf, out);
}